// Round 8
// baseline (70.516 us; speedup 1.0000x reference)
//
#include <hip/hip_runtime.h>
#include <stdint.h>

#define NB   8
#define INC  64
#define INN  20000
#define OUTC 64
#define OUTN 8000
#define MAXD 32

// ---------- kernel 1: xT[b][i][c] = bf16(x[b][c][i] * w[c][i])  (+ prep plane) ----------
// grid (313, 9): y=0..7 -> transpose for batch y; y==8 -> prep (AQ/scale2/W_T).
__global__ __launch_bounds__(256)
void xt_prep_kernel(const float* __restrict__ x, const float* __restrict__ w,
                    const int* __restrict__ A, const float* __restrict__ mask,
                    const float* __restrict__ ct_v, const float* __restrict__ ct_g,
                    ushort* __restrict__ xT, uint4* __restrict__ AQ,
                    float2* __restrict__ scale2, float* __restrict__ W_T) {
    int t = threadIdx.x;
    if (blockIdx.y == 8) {
        int flat = blockIdx.x;
        if (flat == 64) {
            int k = t;
            if (k < OUTC) {
                float s = 0.f;
                for (int c = 0; c < INC; ++c) { float v = ct_v[k * INC + c]; s += v * v; }
                float inv = ct_g[k] / sqrtf(s);
                for (int c = 0; c < INC; ++c) W_T[c * OUTC + k] = ct_v[k * INC + c] * inv;
            }
            return;
        }
        if (flat > 64 || t >= 128) return;
        int o = flat * 128 + t;
        if (o >= OUTN) return;
        const int4* arow = (const int4*)(A + (size_t)o * MAXD);
#pragma unroll
        for (int j = 0; j < 4; ++j) {
            int4 v0 = arow[2 * j];
            int4 v1 = arow[2 * j + 1];
            uint4 pk;   // 8 u16 (idx<<1); idx<20000 so (idx<<1)<40000 fits u16
            pk.x = (uint32_t)(v0.x << 1) | ((uint32_t)(v0.y << 1) << 16);
            pk.y = (uint32_t)(v0.z << 1) | ((uint32_t)(v0.w << 1) << 16);
            pk.z = (uint32_t)(v1.x << 1) | ((uint32_t)(v1.y << 1) << 16);
            pk.w = (uint32_t)(v1.z << 1) | ((uint32_t)(v1.w << 1) << 16);
            AQ[(size_t)j * OUTN + o] = pk;
        }
        float invdeg = mask[(size_t)o * MAXD];
        float deg    = rintf(1.0f / invdeg);
        scale2[o] = make_float2(invdeg, 32.0f - deg);
        return;
    }

    // ---- transpose path: 64-i tile ----
    __shared__ ushort tile[64][68];       // padded; 8,704 B
    int b  = blockIdx.y;
    int i0 = blockIdx.x * 64;
    int il = (t & 15) * 4;                // i offset 0..60, step 4
    int cb = t >> 4;                      // 0..15

#pragma unroll
    for (int cl = 0; cl < 4; ++cl) {
        int c = cb + cl * 16;
        int i = i0 + il;
        if (i < INN) {                    // INN%4==0 -> whole float4 valid
            float4 xv = *(const float4*)(x + ((size_t)b * INC + c) * INN + i);
            float4 wv = *(const float4*)(w + (size_t)c * INN + i);
            float p0 = xv.x * wv.x, p1 = xv.y * wv.y, p2 = xv.z * wv.z, p3 = xv.w * wv.w;
            uint32_t u0 = (__float_as_uint(p0) + 0x7FFFu + ((__float_as_uint(p0) >> 16) & 1u)) >> 16;
            uint32_t u1 = (__float_as_uint(p1) + 0x7FFFu + ((__float_as_uint(p1) >> 16) & 1u)) >> 16;
            uint32_t u2 = (__float_as_uint(p2) + 0x7FFFu + ((__float_as_uint(p2) >> 16) & 1u)) >> 16;
            uint32_t u3 = (__float_as_uint(p3) + 0x7FFFu + ((__float_as_uint(p3) >> 16) & 1u)) >> 16;
            uint2 pk = make_uint2((u0 & 0xFFFFu) | (u1 << 16), (u2 & 0xFFFFu) | (u3 << 16));
            *(uint2*)(&tile[c][il]) = pk;
        }
    }
    __syncthreads();

    // write-out: thread t -> row i_loc = t>>2, 32B chunk h = t&3
    int i_loc = t >> 2;
    int h     = t & 3;
    int i     = i0 + i_loc;
    if (i < INN) {
        ushort s[16];
#pragma unroll
        for (int j = 0; j < 16; ++j) s[j] = tile[h * 16 + j][i_loc];
        uint4 a0, a1;
        a0.x = (uint32_t)s[0]  | ((uint32_t)s[1]  << 16);
        a0.y = (uint32_t)s[2]  | ((uint32_t)s[3]  << 16);
        a0.z = (uint32_t)s[4]  | ((uint32_t)s[5]  << 16);
        a0.w = (uint32_t)s[6]  | ((uint32_t)s[7]  << 16);
        a1.x = (uint32_t)s[8]  | ((uint32_t)s[9]  << 16);
        a1.y = (uint32_t)s[10] | ((uint32_t)s[11] << 16);
        a1.z = (uint32_t)s[12] | ((uint32_t)s[13] << 16);
        a1.w = (uint32_t)s[14] | ((uint32_t)s[15] << 16);
        uint32_t* dst = (uint32_t*)(xT + ((size_t)(b * INN + i)) * 64 + h * 16);
        *(uint4*)(dst)     = a0;
        *(uint4*)(dst + 4) = a1;
    }
}

// ---------- kernel 2: L2-direct cacheline gather (lane = channel) ----------
// 1D grid 504: b = id%8 (XCD affinity), chunk = id/8 (128 o's). 256 thr = 4 waves.
__global__ __launch_bounds__(256, 8)
void gather_kernel(const ushort* __restrict__ xT, const uint4* __restrict__ AQ,
                   const float2* __restrict__ scale2, float* __restrict__ pooled) {
    __shared__ float trans[128][65];      // 33,280 B
    int id    = blockIdx.x;
    int b     = id & 7;
    int chunk = id >> 3;                  // 0..62
    int o0    = chunk * 128;
    int t     = threadIdx.x;
    int lane  = t & 63;
    int wid   = t >> 6;

    const char* xTb = (const char*)(xT + (size_t)b * INN * 64);
    int lane2 = lane * 2;
    float zv;
    { ushort u = *(const ushort*)(xTb + lane2); zv = __uint_as_float((uint32_t)u << 16); }

#pragma unroll 2
    for (int it = 0; it < 32; ++it) {
        int o = o0 + wid * 32 + it;
        if (o < OUTN) {
            uint4 q0 = AQ[o];
            uint4 q1 = AQ[OUTN + o];
            uint4 q2 = AQ[2 * OUTN + o];
            uint4 q3 = AQ[3 * OUTN + o];
            float acc = 0.f;
#define DOW(word)                                                               \
            {                                                                   \
                uint32_t uu = (uint32_t)__builtin_amdgcn_readfirstlane((int)(word)); \
                uint32_t lo = (uu & 0xFFFFu) << 6;                              \
                uint32_t hi = (uu >> 16) << 6;                                  \
                ushort v0 = *(const ushort*)(xTb + lo + lane2);                 \
                ushort v1 = *(const ushort*)(xTb + hi + lane2);                 \
                acc += __uint_as_float((uint32_t)v0 << 16);                     \
                acc += __uint_as_float((uint32_t)v1 << 16);                     \
            }
            DOW(q0.x) DOW(q0.y) DOW(q0.z) DOW(q0.w)
            DOW(q1.x) DOW(q1.y) DOW(q1.z) DOW(q1.w)
            DOW(q2.x) DOW(q2.y) DOW(q2.z) DOW(q2.w)
            DOW(q3.x) DOW(q3.y) DOW(q3.z) DOW(q3.w)
#undef DOW
            float2 sc = scale2[o];        // {1/deg, 32-deg}
            trans[o - o0][lane] = (acc - sc.y * zv) * sc.x;
        }
    }
    __syncthreads();

    // coalesced write-out: pooled[b][c][o0 .. o0+count)
    int count = OUTN - o0; if (count > 128) count = 128;
#pragma unroll
    for (int rep = 0; rep < 8; ++rep) {
        int j  = t + rep * 256;           // 0..2047
        int c  = j >> 5;
        int oq = (j & 31) * 4;
        if (oq < count) {
            float4 v = make_float4(trans[oq][c], trans[oq + 1][c],
                                   trans[oq + 2][c], trans[oq + 3][c]);
            *(float4*)(pooled + ((size_t)(b * OUTC + c)) * OUTN + o0 + oq) = v;
        }
    }
}

// ---------- kernel 3: y = W @ pooled + bias (in place over d_out) ----------
__global__ __launch_bounds__(256)
void out_kernel(float* io, const float* __restrict__ W_T,
                const float* __restrict__ bias) {
    __shared__ __align__(16) float sp[INC][128];
    __shared__ __align__(16) float sw[INC][OUTC];
    int obase = blockIdx.x * 128;
    int b     = blockIdx.y;

    const float* pb = io + (size_t)b * INC * OUTN;
    for (int idx = threadIdx.x; idx < INC * 32; idx += 256) {
        int c  = idx >> 5;
        int q  = idx & 31;
        int o4 = obase + q * 4;
        float4 v = (o4 < OUTN) ? *(const float4*)(pb + (size_t)c * OUTN + o4)
                               : make_float4(0.f, 0.f, 0.f, 0.f);
        *(float4*)(&sp[c][q * 4]) = v;
    }
    for (int idx = threadIdx.x; idx < (INC * OUTC) / 4; idx += 256) {
        ((float4*)sw)[idx] = ((const float4*)W_T)[idx];
    }
    __syncthreads();

    int t   = threadIdx.x;
    int kt  = t >> 4;
    int ot0 = (t & 15) * 8;
    int k0  = kt * 4;

    float acc[4][8];
#pragma unroll
    for (int kk = 0; kk < 4; ++kk) {
#pragma unroll
        for (int jh = 0; jh < 2; ++jh) {
            int o4 = obase + ot0 + jh * 4;
            float4 bv = (o4 < OUTN)
                ? *(const float4*)(bias + (size_t)(k0 + kk) * OUTN + o4)
                : make_float4(0.f, 0.f, 0.f, 0.f);
            acc[kk][jh * 4 + 0] = bv.x;
            acc[kk][jh * 4 + 1] = bv.y;
            acc[kk][jh * 4 + 2] = bv.z;
            acc[kk][jh * 4 + 3] = bv.w;
        }
    }

#pragma unroll 4
    for (int c = 0; c < INC; ++c) {
        float4 w4  = *(const float4*)(&sw[c][k0]);
        float4 pa  = *(const float4*)(&sp[c][ot0]);
        float4 pb4 = *(const float4*)(&sp[c][ot0 + 4]);
        float p[8] = {pa.x, pa.y, pa.z, pa.w, pb4.x, pb4.y, pb4.z, pb4.w};
        float wv[4] = {w4.x, w4.y, w4.z, w4.w};
#pragma unroll
        for (int kk = 0; kk < 4; ++kk)
#pragma unroll
            for (int j = 0; j < 8; ++j)
                acc[kk][j] += wv[kk] * p[j];
    }

    int o0 = obase + ot0;
    if (o0 < OUTN) {
#pragma unroll
        for (int kk = 0; kk < 4; ++kk) {
            float4 s0 = make_float4(acc[kk][0], acc[kk][1], acc[kk][2], acc[kk][3]);
            float4 s1 = make_float4(acc[kk][4], acc[kk][5], acc[kk][6], acc[kk][7]);
            float* dst = io + ((size_t)(b * OUTC + k0 + kk)) * OUTN + o0;
            *(float4*)(dst)     = s0;
            *(float4*)(dst + 4) = s1;
        }
    }
}

// ---------- launch ----------
extern "C" void kernel_launch(void* const* d_in, const int* in_sizes, int n_in,
                              void* d_out, int out_size, void* d_ws, size_t ws_size,
                              hipStream_t stream) {
    const float* x    = (const float*)d_in[0];
    const float* w    = (const float*)d_in[1];
    const float* ct_v = (const float*)d_in[2];
    const float* ct_g = (const float*)d_in[3];
    const float* bias = (const float*)d_in[4];
    const float* mask = (const float*)d_in[5];
    const int*   A    = (const int*)d_in[6];
    float* y = (float*)d_out;

    char* ws = (char*)d_ws;
    ushort* xT     = (ushort*)(ws);                   // 8*20000*64*2 = 20,480,000 B
    uint4*  AQ     = (uint4*)(ws + 20480000);         // 4*8000*16    =    512,000 B
    float2* scale2 = (float2*)(ws + 20992000);        // 8000*8       =     64,000 B
    float*  W_T    = (float*)(ws + 21056000);         // 64*64*4      =     16,384 B

    xt_prep_kernel<<<dim3(313, 9), 256, 0, stream>>>(x, w, A, mask, ct_v, ct_g,
                                                     xT, AQ, scale2, W_T);
    gather_kernel<<<504, 256, 0, stream>>>(xT, AQ, scale2, y);
    out_kernel<<<dim3(63, NB), 256, 0, stream>>>(y, W_T, bias);
}

// Round 9
// 48.391 us; speedup vs baseline: 1.4572x; 1.4572x over previous
//
#include <hip/hip_runtime.h>
#include <stdint.h>

#define NB   8
#define INC  64
#define INN  20000
#define OUTC 64
#define OUTN 8000
#define MAXD 32

typedef float f32x2 __attribute__((ext_vector_type(2)));

// ---------- kernel 1: xT8[b][i][c] = fp8(x[b][c][i]*w[c][i]*256)  (+ prep plane) ----------
// grid (313, 9): y=0..7 -> transpose for batch y; y==8 -> prep (AQ4/scale2/W_T).
__global__ __launch_bounds__(256)
void xt_prep_kernel(const float* __restrict__ x, const float* __restrict__ w,
                    const int* __restrict__ A, const float* __restrict__ mask,
                    const float* __restrict__ ct_v, const float* __restrict__ ct_g,
                    unsigned char* __restrict__ xT8, uint4* __restrict__ AQ4,
                    float2* __restrict__ scale2, float* __restrict__ W_T) {
    int t = threadIdx.x;
    if (blockIdx.y == 8) {
        int flat = blockIdx.x;
        if (flat == 64) {
            int k = t;
            if (k < OUTC) {
                float s = 0.f;
                for (int c = 0; c < INC; ++c) { float v = ct_v[k * INC + c]; s += v * v; }
                float inv = ct_g[k] / sqrtf(s);
                for (int c = 0; c < INC; ++c) W_T[c * OUTC + k] = ct_v[k * INC + c] * inv;
            }
            return;
        }
        if (flat > 64 || t >= 128) return;
        int o = flat * 128 + t;
        if (o >= OUTN) return;
        const int4* arow = (const int4*)(A + (size_t)o * MAXD);
#pragma unroll
        for (int j = 0; j < 4; ++j) {
            int4 v0 = arow[2 * j];
            int4 v1 = arow[2 * j + 1];
            uint4 pk;   // 8 raw u16 indices (idx < 20000 fits u16), o-major
            pk.x = (uint32_t)v0.x | ((uint32_t)v0.y << 16);
            pk.y = (uint32_t)v0.z | ((uint32_t)v0.w << 16);
            pk.z = (uint32_t)v1.x | ((uint32_t)v1.y << 16);
            pk.w = (uint32_t)v1.z | ((uint32_t)v1.w << 16);
            AQ4[(size_t)o * 4 + j] = pk;
        }
        float invdeg = mask[(size_t)o * MAXD];
        float deg    = rintf(1.0f / invdeg);
        scale2[o] = make_float2(invdeg * (1.0f / 256.0f), 32.0f - deg);
        return;
    }

    // ---- transpose path: 64-i tile, f32 staging ----
    __shared__ float tile[64][68];        // 17,408 B
    int b  = blockIdx.y;
    int i0 = blockIdx.x * 64;
    int il = (t & 15) * 4;                // i offset 0..60, step 4
    int cb = t >> 4;                      // 0..15

#pragma unroll
    for (int cl = 0; cl < 4; ++cl) {
        int c = cb + cl * 16;
        int i = i0 + il;
        if (i < INN) {                    // INN%4==0 -> whole float4 valid
            float4 xv = *(const float4*)(x + ((size_t)b * INC + c) * INN + i);
            float4 wv = *(const float4*)(w + (size_t)c * INN + i);
            float4 p = make_float4(xv.x * wv.x * 256.0f, xv.y * wv.y * 256.0f,
                                   xv.z * wv.z * 256.0f, xv.w * wv.w * 256.0f);
            *(float4*)(&tile[c][il]) = p;
        }
    }
    __syncthreads();

    // write-out: thread t -> row i_loc = t>>2, 16B chunk h = t&3 (16 channels)
    int i_loc = t >> 2;
    int h     = t & 3;
    int i     = i0 + i_loc;
    if (i < INN) {
        int c0 = h * 16;
        float s[16];
#pragma unroll
        for (int j = 0; j < 16; ++j) s[j] = tile[c0 + j][i_loc];
        uint4 out;
        uint32_t u;
        u = __builtin_amdgcn_cvt_pk_fp8_f32(s[0],  s[1],  0, false);
        u = __builtin_amdgcn_cvt_pk_fp8_f32(s[2],  s[3],  u, true);
        out.x = u;
        u = __builtin_amdgcn_cvt_pk_fp8_f32(s[4],  s[5],  0, false);
        u = __builtin_amdgcn_cvt_pk_fp8_f32(s[6],  s[7],  u, true);
        out.y = u;
        u = __builtin_amdgcn_cvt_pk_fp8_f32(s[8],  s[9],  0, false);
        u = __builtin_amdgcn_cvt_pk_fp8_f32(s[10], s[11], u, true);
        out.z = u;
        u = __builtin_amdgcn_cvt_pk_fp8_f32(s[12], s[13], 0, false);
        u = __builtin_amdgcn_cvt_pk_fp8_f32(s[14], s[15], u, true);
        out.w = u;
        *(uint4*)(xT8 + ((size_t)(b * INN + i)) * 64 + h * 16) = out;
    }
}

// ---------- kernel 2: L2-direct vector gather (wave = 8 o x 8 chgrp) ----------
// grid 2000 = 250 chunks x 8 b; flat&7 = b pins batch b to XCD b. 256 thr = 4 waves.
__global__ __launch_bounds__(256, 4)
void gather_kernel(const unsigned char* __restrict__ xT8, const uint4* __restrict__ AQ4,
                   const float2* __restrict__ scale2, float* __restrict__ pooled) {
    __shared__ float trans[32][68];       // 8,704 B
    int flat  = blockIdx.x;
    int b     = flat & 7;
    int chunk = flat >> 3;                // 0..249
    int o0    = chunk * 32;
    int t     = threadIdx.x;
    int lane  = t & 63;
    int wid   = t >> 6;
    int osub  = lane >> 3;
    int chgrp = lane & 7;
    int oloc  = wid * 8 + osub;
    int o     = o0 + oloc;                // < 8000 always

    const char* xTb = (const char*)xT8 + (size_t)b * INN * 64 + chgrp * 8;

    // per-lane index registers: 32 u16 indices for this lane's o
    const uint4* aq = AQ4 + (size_t)o * 4;
    uint4 q0 = aq[0], q1 = aq[1], q2 = aq[2], q3 = aq[3];
    float2 sc = scale2[o];                // {invdeg/256, 32-deg}
    uint2  zw = *(const uint2*)(xTb);     // xw[b][0][chgrp*8..+8] fp8

    float a0 = 0.f, a1 = 0.f, a2 = 0.f, a3 = 0.f;
    float a4 = 0.f, a5 = 0.f, a6 = 0.f, a7 = 0.f;

#define DOI(idx)                                                        \
    {                                                                   \
        uint2 v = *(const uint2*)(xTb + ((size_t)(idx) << 6));          \
        f32x2 e;                                                        \
        e = __builtin_amdgcn_cvt_pk_f32_fp8(v.x, false);                \
        a0 += e.x; a1 += e.y;                                           \
        e = __builtin_amdgcn_cvt_pk_f32_fp8(v.x, true);                 \
        a2 += e.x; a3 += e.y;                                           \
        e = __builtin_amdgcn_cvt_pk_f32_fp8(v.y, false);                \
        a4 += e.x; a5 += e.y;                                           \
        e = __builtin_amdgcn_cvt_pk_f32_fp8(v.y, true);                 \
        a6 += e.x; a7 += e.y;                                           \
    }
#define DOU(u) DOI((u) & 0xFFFFu) DOI((u) >> 16)
    DOU(q0.x) DOU(q0.y) DOU(q0.z) DOU(q0.w)
    DOU(q1.x) DOU(q1.y) DOU(q1.z) DOU(q1.w)
    DOU(q2.x) DOU(q2.y) DOU(q2.z) DOU(q2.w)
    DOU(q3.x) DOU(q3.y) DOU(q3.z) DOU(q3.w)
#undef DOU
#undef DOI

    // correction (A pads with idx 0) + scale
    f32x2 e0 = __builtin_amdgcn_cvt_pk_f32_fp8(zw.x, false);
    f32x2 e1 = __builtin_amdgcn_cvt_pk_f32_fp8(zw.x, true);
    f32x2 e2 = __builtin_amdgcn_cvt_pk_f32_fp8(zw.y, false);
    f32x2 e3 = __builtin_amdgcn_cvt_pk_f32_fp8(zw.y, true);
    float4 r0 = make_float4((a0 - sc.y * e0.x) * sc.x, (a1 - sc.y * e0.y) * sc.x,
                            (a2 - sc.y * e1.x) * sc.x, (a3 - sc.y * e1.y) * sc.x);
    float4 r1 = make_float4((a4 - sc.y * e2.x) * sc.x, (a5 - sc.y * e2.y) * sc.x,
                            (a6 - sc.y * e3.x) * sc.x, (a7 - sc.y * e3.y) * sc.x);
    *(float4*)(&trans[oloc][chgrp * 8])     = r0;
    *(float4*)(&trans[oloc][chgrp * 8 + 4]) = r1;
    __syncthreads();

    // coalesced write-out: pooled[b][c][o0..o0+32)
#pragma unroll
    for (int rep = 0; rep < 2; ++rep) {
        int j  = t + rep * 256;           // 0..511
        int c  = j >> 3;
        int oq = (j & 7) * 4;
        float4 v = make_float4(trans[oq][c], trans[oq + 1][c],
                               trans[oq + 2][c], trans[oq + 3][c]);
        *(float4*)(pooled + ((size_t)(b * OUTC + c)) * OUTN + o0 + oq) = v;
    }
}

// ---------- kernel 3: y = W @ pooled + bias (in place over d_out) ----------
__global__ __launch_bounds__(256)
void out_kernel(float* io, const float* __restrict__ W_T,
                const float* __restrict__ bias) {
    __shared__ __align__(16) float sp[INC][128];
    __shared__ __align__(16) float sw[INC][OUTC];
    int obase = blockIdx.x * 128;
    int b     = blockIdx.y;

    const float* pb = io + (size_t)b * INC * OUTN;
    for (int idx = threadIdx.x; idx < INC * 32; idx += 256) {
        int c  = idx >> 5;
        int q  = idx & 31;
        int o4 = obase + q * 4;
        float4 v = (o4 < OUTN) ? *(const float4*)(pb + (size_t)c * OUTN + o4)
                               : make_float4(0.f, 0.f, 0.f, 0.f);
        *(float4*)(&sp[c][q * 4]) = v;
    }
    for (int idx = threadIdx.x; idx < (INC * OUTC) / 4; idx += 256) {
        ((float4*)sw)[idx] = ((const float4*)W_T)[idx];
    }
    __syncthreads();

    int t   = threadIdx.x;
    int kt  = t >> 4;
    int ot0 = (t & 15) * 8;
    int k0  = kt * 4;

    float acc[4][8];
#pragma unroll
    for (int kk = 0; kk < 4; ++kk) {
#pragma unroll
        for (int jh = 0; jh < 2; ++jh) {
            int o4 = obase + ot0 + jh * 4;
            float4 bv = (o4 < OUTN)
                ? *(const float4*)(bias + (size_t)(k0 + kk) * OUTN + o4)
                : make_float4(0.f, 0.f, 0.f, 0.f);
            acc[kk][jh * 4 + 0] = bv.x;
            acc[kk][jh * 4 + 1] = bv.y;
            acc[kk][jh * 4 + 2] = bv.z;
            acc[kk][jh * 4 + 3] = bv.w;
        }
    }

#pragma unroll 4
    for (int c = 0; c < INC; ++c) {
        float4 w4  = *(const float4*)(&sw[c][k0]);
        float4 pa  = *(const float4*)(&sp[c][ot0]);
        float4 pb4 = *(const float4*)(&sp[c][ot0 + 4]);
        float p[8] = {pa.x, pa.y, pa.z, pa.w, pb4.x, pb4.y, pb4.z, pb4.w};
        float wv[4] = {w4.x, w4.y, w4.z, w4.w};
#pragma unroll
        for (int kk = 0; kk < 4; ++kk)
#pragma unroll
            for (int j = 0; j < 8; ++j)
                acc[kk][j] += wv[kk] * p[j];
    }

    int o0 = obase + ot0;
    if (o0 < OUTN) {
#pragma unroll
        for (int kk = 0; kk < 4; ++kk) {
            float4 s0 = make_float4(acc[kk][0], acc[kk][1], acc[kk][2], acc[kk][3]);
            float4 s1 = make_float4(acc[kk][4], acc[kk][5], acc[kk][6], acc[kk][7]);
            float* dst = io + ((size_t)(b * OUTC + k0 + kk)) * OUTN + o0;
            *(float4*)(dst)     = s0;
            *(float4*)(dst + 4) = s1;
        }
    }
}

// ---------- launch ----------
extern "C" void kernel_launch(void* const* d_in, const int* in_sizes, int n_in,
                              void* d_out, int out_size, void* d_ws, size_t ws_size,
                              hipStream_t stream) {
    const float* x    = (const float*)d_in[0];
    const float* w    = (const float*)d_in[1];
    const float* ct_v = (const float*)d_in[2];
    const float* ct_g = (const float*)d_in[3];
    const float* bias = (const float*)d_in[4];
    const float* mask = (const float*)d_in[5];
    const int*   A    = (const int*)d_in[6];
    float* y = (float*)d_out;

    char* ws = (char*)d_ws;
    unsigned char* xT8 = (unsigned char*)(ws);        // 8*20000*64 = 10,240,000 B
    uint4*  AQ4    = (uint4*)(ws + 10240000);         // 8000*64    =    512,000 B
    float2* scale2 = (float2*)(ws + 10752000);        // 8000*8     =     64,000 B
    float*  W_T    = (float*)(ws + 10816000);         // 64*64*4    =     16,384 B

    xt_prep_kernel<<<dim3(313, 9), 256, 0, stream>>>(x, w, A, mask, ct_v, ct_g,
                                                     xT8, AQ4, scale2, W_T);
    gather_kernel<<<2000, 256, 0, stream>>>(xT8, AQ4, scale2, y);
    out_kernel<<<dim3(63, NB), 256, 0, stream>>>(y, W_T, bias);
}